// Round 1
// baseline (5216.571 us; speedup 1.0000x reference)
//
#include <hip/hip_runtime.h>

#define BM 64
#define NTHREADS 512

typedef __attribute__((ext_vector_type(8))) short short8;
typedef __attribute__((ext_vector_type(4))) float f32x4;

__device__ __forceinline__ short f2bf(float f) {
  unsigned u = __builtin_bit_cast(unsigned, f);
  u += 0x7FFFu + ((u >> 16) & 1u);   // RNE
  return (short)(u >> 16);
}
__device__ __forceinline__ float bf2f(short s) {
  unsigned u = ((unsigned)(unsigned short)s) << 16;
  return __builtin_bit_cast(float, u);
}
__device__ __forceinline__ float elu_f(float v) {
  return v > 0.f ? v : (__expf(v) - 1.f);
}

struct Params {
  const float* h;
  const int* idxs;
  const short *W0f, *W0r, *W1, *W2, *W3, *Wt0, *Wt1, *Wc0;
  const float *bs0, *bs1, *bs2, *bs3, *bt0, *bt1, *bt2, *bc0, *bc1;
  const float *Wt2, *Wc1;
  float* out;
  int n_tors;
};

// ---- pack f32 [K][N] weight into bf16 MFMA-fragment order ----
// tile t = (n0/16)*(K/32) + (k0/32); within tile, lane l holds 8 bf16:
//   W[k0 + (l>>4)*8 + j][n0 + (l&15)]  stored at dst + t*512 + l*8
// rev=1 reverses the four 256-row blocks of K=1024 (x_rev @ Ws0 == x_fwd @ W0r).
__global__ __launch_bounds__(256) void pack_w(const float* __restrict__ src,
                                              short* __restrict__ dst,
                                              int K, int N, int rev) {
  int tile = blockIdx.x * 4 + (threadIdx.x >> 6);
  int lane = threadIdx.x & 63;
  int ktiles = K >> 5;
  int tot = (N >> 4) * ktiles;
  if (tile >= tot) return;
  int nt = tile / ktiles, kt = tile - nt * ktiles;
  int col = (nt << 4) + (lane & 15);
  int k0 = (kt << 5) + ((lane >> 4) << 3);
  short8 o;
#pragma unroll
  for (int j = 0; j < 8; ++j) {
    int kr = k0 + j;
    if (rev) kr = ((3 - (kr >> 8)) << 8) | (kr & 255);
    o[j] = f2bf(src[(size_t)kr * N + col]);
  }
  *(short8*)(dst + (size_t)tile * 512 + lane * 8) = o;
}

// A-frag: row = rt*16 + (lane&15), k = kt*32 + (lane>>4)*8 + j  (ds_read_b128)
__device__ __forceinline__ short8 lds_afrag(const char* base, int stride, int rt,
                                            int kt, int lane) {
  int row = rt * 16 + (lane & 15);
  int boff = (kt << 6) + ((lane >> 4) << 4);
  return *(const short8*)(base + row * stride + (boff ^ ((row & 7) << 4)));
}
__device__ __forceinline__ short8 ldg_bfrag(const short* W, int ktiles, int ct,
                                            int kt, int lane) {
  return *(const short8*)(W + ((size_t)(ct * ktiles + kt) << 9) + (lane << 3));
}

// dual-chain residual layer, in-place: h{f,r} = h{f,r} + elu(h{f,r} @ W + b)
__device__ __forceinline__ void layer_dual(char* hf, char* hr,
                                           const short* __restrict__ W,
                                           const float* __restrict__ bias,
                                           int wv, int lane) {
  f32x4 accf[4][4], accr[4][4];
  const f32x4 z = {0.f, 0.f, 0.f, 0.f};
#pragma unroll
  for (int rt = 0; rt < 4; ++rt)
#pragma unroll
    for (int cf = 0; cf < 4; ++cf) { accf[rt][cf] = z; accr[rt][cf] = z; }
  for (int kt = 0; kt < 16; ++kt) {
    short8 af[4], ar[4], b[4];
#pragma unroll
    for (int rt = 0; rt < 4; ++rt) {
      af[rt] = lds_afrag(hf, 1024, rt, kt, lane);
      ar[rt] = lds_afrag(hr, 1024, rt, kt, lane);
    }
#pragma unroll
    for (int cf = 0; cf < 4; ++cf) b[cf] = ldg_bfrag(W, 16, (wv << 2) + cf, kt, lane);
#pragma unroll
    for (int rt = 0; rt < 4; ++rt)
#pragma unroll
      for (int cf = 0; cf < 4; ++cf) {
        accf[rt][cf] = __builtin_amdgcn_mfma_f32_16x16x32_bf16(af[rt], b[cf], accf[rt][cf], 0, 0, 0);
        accr[rt][cf] = __builtin_amdgcn_mfma_f32_16x16x32_bf16(ar[rt], b[cf], accr[rt][cf], 0, 0, 0);
      }
  }
  float bcol[4];
#pragma unroll
  for (int cf = 0; cf < 4; ++cf) bcol[cf] = bias[(wv << 6) + (cf << 4) + (lane & 15)];
  __syncthreads();  // all A-frag reads complete before in-place update
#pragma unroll
  for (int rt = 0; rt < 4; ++rt)
#pragma unroll
    for (int cf = 0; cf < 4; ++cf) {
      int col = (wv << 6) + (cf << 4) + (lane & 15);
#pragma unroll
      for (int i = 0; i < 4; ++i) {
        int row = rt * 16 + ((lane >> 4) << 2) + i;
        size_t off = (size_t)row * 1024 + ((col * 2) ^ ((row & 7) << 4));
        short* pf = (short*)(hf + off);
        short* pr = (short*)(hr + off);
        *pf = f2bf(bf2f(*pf) + elu_f(accf[rt][cf][i] + bcol[cf]));
        *pr = f2bf(bf2f(*pr) + elu_f(accr[rt][cf][i] + bcol[cf]));
      }
    }
  __syncthreads();
}

// single-chain layer: out = res + elu(in @ W + b)   (out may alias in/res)
__device__ __forceinline__ void layer_single(const char* in,
                                             const short* __restrict__ W,
                                             const float* __restrict__ bias,
                                             const char* res, char* out,
                                             int wv, int lane) {
  f32x4 acc[4][4];
  const f32x4 z = {0.f, 0.f, 0.f, 0.f};
#pragma unroll
  for (int rt = 0; rt < 4; ++rt)
#pragma unroll
    for (int cf = 0; cf < 4; ++cf) acc[rt][cf] = z;
  for (int kt = 0; kt < 16; ++kt) {
    short8 a[4], b[4];
#pragma unroll
    for (int rt = 0; rt < 4; ++rt) a[rt] = lds_afrag(in, 1024, rt, kt, lane);
#pragma unroll
    for (int cf = 0; cf < 4; ++cf) b[cf] = ldg_bfrag(W, 16, (wv << 2) + cf, kt, lane);
#pragma unroll
    for (int rt = 0; rt < 4; ++rt)
#pragma unroll
      for (int cf = 0; cf < 4; ++cf)
        acc[rt][cf] = __builtin_amdgcn_mfma_f32_16x16x32_bf16(a[rt], b[cf], acc[rt][cf], 0, 0, 0);
  }
  float bcol[4];
#pragma unroll
  for (int cf = 0; cf < 4; ++cf) bcol[cf] = bias[(wv << 6) + (cf << 4) + (lane & 15)];
  __syncthreads();
#pragma unroll
  for (int rt = 0; rt < 4; ++rt)
#pragma unroll
    for (int cf = 0; cf < 4; ++cf) {
      int col = (wv << 6) + (cf << 4) + (lane & 15);
#pragma unroll
      for (int i = 0; i < 4; ++i) {
        int row = rt * 16 + ((lane >> 4) << 2) + i;
        size_t off = (size_t)row * 1024 + ((col * 2) ^ ((row & 7) << 4));
        float v = elu_f(acc[rt][cf][i] + bcol[cf]) + bf2f(*(const short*)(res + off));
        *(short*)(out + off) = f2bf(v);
      }
    }
  __syncthreads();
}

__global__ __launch_bounds__(NTHREADS) void fused(Params p) {
  __shared__ char smem[BM * 2048];     // 128 KB: x tile [64][1024]bf16; later sA|sB
  __shared__ float sSmall[BM * 12];    // score/coeff stash
  char* sA = smem;
  char* sB = smem + BM * 1024;
  const int tid = threadIdx.x;
  const int lane = tid & 63;
  const int wv = tid >> 6;             // 8 waves, wave owns cols wv*64..wv*64+63
  const int r0 = blockIdx.x * BM;

  // ---- gather x = [f1 f2 f3 f4] as bf16 into swizzled LDS [64][1024] ----
  for (int c = tid; c < BM * 128; c += NTHREADS) {
    int row = c >> 7;
    int col0 = (c & 127) << 3;                  // element col 0..1023, step 8
    int grow = r0 + row;
    short8 o;
    if (grow < p.n_tors) {
      int f = col0 >> 8;
      int cin = col0 & 255;
      int a = p.idxs[(size_t)grow * 4 + f];
      const float4* s4 = (const float4*)(p.h + (size_t)a * 256 + cin);
      float4 v0 = s4[0], v1 = s4[1];
      o[0] = f2bf(v0.x); o[1] = f2bf(v0.y); o[2] = f2bf(v0.z); o[3] = f2bf(v0.w);
      o[4] = f2bf(v1.x); o[5] = f2bf(v1.y); o[6] = f2bf(v1.z); o[7] = f2bf(v1.w);
    } else {
#pragma unroll
      for (int e = 0; e < 8; ++e) o[e] = 0;
    }
    *(short8*)(smem + (size_t)row * 2048 + ((col0 * 2) ^ ((row & 7) << 4))) = o;
  }
  __syncthreads();

  // ---- layer0: hf = elu(x@Ws0+bs0), hr = elu(x@W0r+bs0), K=1024, dual B ----
  {
    f32x4 accf[4][4], accr[4][4];
    const f32x4 z = {0.f, 0.f, 0.f, 0.f};
#pragma unroll
    for (int rt = 0; rt < 4; ++rt)
#pragma unroll
      for (int cf = 0; cf < 4; ++cf) { accf[rt][cf] = z; accr[rt][cf] = z; }
    for (int kt = 0; kt < 32; ++kt) {
      short8 a[4], bfw[4], brw[4];
#pragma unroll
      for (int rt = 0; rt < 4; ++rt) a[rt] = lds_afrag(smem, 2048, rt, kt, lane);
#pragma unroll
      for (int cf = 0; cf < 4; ++cf) {
        bfw[cf] = ldg_bfrag(p.W0f, 32, (wv << 2) + cf, kt, lane);
        brw[cf] = ldg_bfrag(p.W0r, 32, (wv << 2) + cf, kt, lane);
      }
#pragma unroll
      for (int rt = 0; rt < 4; ++rt)
#pragma unroll
        for (int cf = 0; cf < 4; ++cf) {
          accf[rt][cf] = __builtin_amdgcn_mfma_f32_16x16x32_bf16(a[rt], bfw[cf], accf[rt][cf], 0, 0, 0);
          accr[rt][cf] = __builtin_amdgcn_mfma_f32_16x16x32_bf16(a[rt], brw[cf], accr[rt][cf], 0, 0, 0);
        }
    }
    float bcol[4];
#pragma unroll
    for (int cf = 0; cf < 4; ++cf) bcol[cf] = p.bs0[(wv << 6) + (cf << 4) + (lane & 15)];
    __syncthreads();  // all x reads done; sA/sB overlay the x region
#pragma unroll
    for (int rt = 0; rt < 4; ++rt)
#pragma unroll
      for (int cf = 0; cf < 4; ++cf) {
        int col = (wv << 6) + (cf << 4) + (lane & 15);
#pragma unroll
        for (int i = 0; i < 4; ++i) {
          int row = rt * 16 + ((lane >> 4) << 2) + i;
          size_t off = (size_t)row * 1024 + ((col * 2) ^ ((row & 7) << 4));
          *(short*)(sA + off) = f2bf(elu_f(accf[rt][cf][i] + bcol[cf]));
          *(short*)(sB + off) = f2bf(elu_f(accr[rt][cf][i] + bcol[cf]));
        }
      }
    __syncthreads();
  }

  // ---- 3 dual-chain residual layers (shared weights) ----
  layer_dual(sA, sB, p.W1, p.bs1, wv, lane);
  layer_dual(sA, sB, p.W2, p.bs2, wv, lane);
  layer_dual(sA, sB, p.W3, p.bs3, wv, lane);

  // ---- sym = hf + hr  -> sA ----
  for (int c = tid; c < BM * 64; c += NTHREADS) {
    int row = c >> 6;
    int col0 = (c & 63) << 3;
    size_t off = (size_t)row * 1024 + ((col0 * 2) ^ ((row & 7) << 4));
    short8 xa = *(short8*)(sA + off);
    short8 xb = *(short8*)(sB + off);
    short8 o;
#pragma unroll
    for (int e = 0; e < 8; ++e) o[e] = f2bf(bf2f(xa[e]) + bf2f(xb[e]));
    *(short8*)(sA + off) = o;
  }
  __syncthreads();

  // ---- heads ----
  layer_single(sA, p.Wt0, p.bt0, sA, sB, wv, lane);  // t0 = sym + elu(sym@Wt0)
  layer_single(sB, p.Wt1, p.bt1, sB, sB, wv, lane);  // t1 = t0 + elu(t0@Wt1)
  layer_single(sA, p.Wc0, p.bc0, sA, sA, wv, lane);  // c  = sym + elu(sym@Wc0)

  // ---- final 512->6 projections: coeffs from t (sB), score from c (sA) ----
  for (int idx = tid; idx < BM * 12; idx += NTHREADS) {
    int row = idx / 12, jj = idx - row * 12;
    int j = (jj < 6) ? jj : jj - 6;
    const char* src = (jj < 6) ? sB : sA;
    const float* W = (jj < 6) ? p.Wt2 : p.Wc1;
    float acc = (jj < 6) ? p.bt2[j] : p.bc1[j];
    for (int c0 = 0; c0 < 512; c0 += 8) {
      short8 v = *(const short8*)(src + (size_t)row * 1024 + ((c0 * 2) ^ ((row & 7) << 4)));
#pragma unroll
      for (int e = 0; e < 8; ++e) acc += bf2f(v[e]) * W[(c0 + e) * 6 + j];
    }
    sSmall[row * 12 + jj] = acc;
  }
  __syncthreads();
  for (int idx = tid; idx < BM * 6; idx += NTHREADS) {
    int row = idx / 6, j = idx - row * 6;
    int grow = r0 + row;
    if (grow < p.n_tors) {
      float score = sSmall[row * 12 + 6 + j];
      float coeff = sSmall[row * 12 + j];
      p.out[(size_t)grow * 6 + j] = score;
      p.out[(size_t)p.n_tors * 6 + (size_t)grow * 6 + j] =
          coeff * 0.001f * (1.0f / (1.0f + __expf(-score)));
    }
  }
}

extern "C" void kernel_launch(void* const* d_in, const int* in_sizes, int n_in,
                              void* d_out, int out_size, void* d_ws, size_t ws_size,
                              hipStream_t stream) {
  const float* h   = (const float*)d_in[0];
  const int* idxs  = (const int*)d_in[1];
  const float* Ws0 = (const float*)d_in[2];
  const float* bs0 = (const float*)d_in[3];
  const float* Ws1 = (const float*)d_in[4];
  const float* bs1 = (const float*)d_in[5];
  const float* Ws2 = (const float*)d_in[6];
  const float* bs2 = (const float*)d_in[7];
  const float* Ws3 = (const float*)d_in[8];
  const float* bs3 = (const float*)d_in[9];
  const float* Wt0 = (const float*)d_in[10];
  const float* bt0 = (const float*)d_in[11];
  const float* Wt1 = (const float*)d_in[12];
  const float* bt1 = (const float*)d_in[13];
  const float* Wt2 = (const float*)d_in[14];
  const float* bt2 = (const float*)d_in[15];
  const float* Wc0 = (const float*)d_in[16];
  const float* bc0 = (const float*)d_in[17];
  const float* Wc1 = (const float*)d_in[18];
  const float* bc1 = (const float*)d_in[19];
  int n_tors = in_sizes[1] / 4;

  // ws layout (shorts): W0f(1M) W0r(1M) W1 W2 W3 Wt0 Wt1 Wc0 (512KB each) = 5 MB
  short* ws = (short*)d_ws;
  short* W0f = ws;
  short* W0r = ws + 524288;
  short* W1  = ws + 1048576;
  short* W2  = W1 + 262144;
  short* W3  = W2 + 262144;
  short* Wt0c = W3 + 262144;
  short* Wt1c = Wt0c + 262144;
  short* Wc0c = Wt1c + 262144;

  auto pk = [&](const float* s, short* dmem, int K, int N, int rev) {
    int tiles = (N >> 4) * (K >> 5);
    pack_w<<<dim3((tiles + 3) / 4), dim3(256), 0, stream>>>(s, dmem, K, N, rev);
  };
  pk(Ws0, W0f, 1024, 512, 0);
  pk(Ws0, W0r, 1024, 512, 1);
  pk(Ws1, W1, 512, 512, 0);
  pk(Ws2, W2, 512, 512, 0);
  pk(Ws3, W3, 512, 512, 0);
  pk(Wt0, Wt0c, 512, 512, 0);
  pk(Wt1, Wt1c, 512, 512, 0);
  pk(Wc0, Wc0c, 512, 512, 0);

  Params p;
  p.h = h; p.idxs = idxs;
  p.W0f = W0f; p.W0r = W0r; p.W1 = W1; p.W2 = W2; p.W3 = W3;
  p.Wt0 = Wt0c; p.Wt1 = Wt1c; p.Wc0 = Wc0c;
  p.bs0 = bs0; p.bs1 = bs1; p.bs2 = bs2; p.bs3 = bs3;
  p.bt0 = bt0; p.bt1 = bt1; p.bt2 = bt2; p.bc0 = bc0; p.bc1 = bc1;
  p.Wt2 = Wt2; p.Wc1 = Wc1;
  p.out = (float*)d_out; p.n_tors = n_tors;

  fused<<<dim3((n_tors + BM - 1) / BM), dim3(NTHREADS), 0, stream>>>(p);
}

// Round 2
// 3434.932 us; speedup vs baseline: 1.5187x; 1.5187x over previous
//
#include <hip/hip_runtime.h>

#define BM 64
#define NTHREADS 512

typedef __attribute__((ext_vector_type(8))) short short8;
typedef __attribute__((ext_vector_type(4))) float f32x4;

__device__ __forceinline__ short f2bf(float f) {
  unsigned u = __builtin_bit_cast(unsigned, f);
  u += 0x7FFFu + ((u >> 16) & 1u);   // RNE
  return (short)(u >> 16);
}
__device__ __forceinline__ float bf2f(short s) {
  unsigned u = ((unsigned)(unsigned short)s) << 16;
  return __builtin_bit_cast(float, u);
}
__device__ __forceinline__ float elu_f(float v) {
  return v > 0.f ? v : (__expf(v) - 1.f);
}

// ---- pack f32 [K][N] weight into bf16 MFMA-fragment order ----
__global__ __launch_bounds__(256) void pack_w(const float* __restrict__ src,
                                              short* __restrict__ dst,
                                              int K, int N, int rev) {
  int tile = blockIdx.x * 4 + (threadIdx.x >> 6);
  int lane = threadIdx.x & 63;
  int ktiles = K >> 5;
  int tot = (N >> 4) * ktiles;
  if (tile >= tot) return;
  int nt = tile / ktiles, kt = tile - nt * ktiles;
  int col = (nt << 4) + (lane & 15);
  int k0 = (kt << 5) + ((lane >> 4) << 3);
  short8 o;
#pragma unroll
  for (int j = 0; j < 8; ++j) {
    int kr = k0 + j;
    if (rev) kr = ((3 - (kr >> 8)) << 8) | (kr & 255);
    o[j] = f2bf(src[(size_t)kr * N + col]);
  }
  *(short8*)(dst + (size_t)tile * 512 + lane * 8) = o;
}

__device__ __forceinline__ short8 lds_afrag(const char* base, int stride, int rt,
                                            int kt, int lane) {
  int row = rt * 16 + (lane & 15);
  int boff = (kt << 6) + ((lane >> 4) << 4);
  return *(const short8*)(base + row * stride + (boff ^ ((row & 7) << 4)));
}
__device__ __forceinline__ short8 ldg_bfrag(const short* W, int ktiles, int ct,
                                            int kt, int lane) {
  return *(const short8*)(W + ((size_t)(ct * ktiles + kt) << 9) + (lane << 3));
}

// ================= NEW PATH =================

// p[a][s][c] = h_a(256) @ Ws0[256s:256s+256, :]   (bf16, [n_atoms][4][512])
__global__ __launch_bounds__(NTHREADS) void atom_pre(const float* __restrict__ h,
                                                     const short* __restrict__ W0f,
                                                     short* __restrict__ p,
                                                     int n_atoms) {
  __shared__ char sh[BM * 512];   // 64 rows x 256 bf16, swizzled
  const int tid = threadIdx.x, lane = tid & 63, wv = tid >> 6;
  const int r0 = blockIdx.x * BM;
  for (int i = tid; i < BM * 32; i += NTHREADS) {
    int row = i >> 5, c0 = (i & 31) << 3;
    int ga = r0 + row;
    short8 o;
    if (ga < n_atoms) {
      const float4* s4 = (const float4*)(h + (size_t)ga * 256 + c0);
      float4 v0 = s4[0], v1 = s4[1];
      o[0] = f2bf(v0.x); o[1] = f2bf(v0.y); o[2] = f2bf(v0.z); o[3] = f2bf(v0.w);
      o[4] = f2bf(v1.x); o[5] = f2bf(v1.y); o[6] = f2bf(v1.z); o[7] = f2bf(v1.w);
    } else {
#pragma unroll
      for (int e = 0; e < 8; ++e) o[e] = 0;
    }
    *(short8*)(sh + row * 512 + ((c0 * 2) ^ ((row & 7) << 4))) = o;
  }
  __syncthreads();
#pragma unroll 1
  for (int s = 0; s < 4; ++s) {
    f32x4 acc[4][4];
    const f32x4 z = {0.f, 0.f, 0.f, 0.f};
#pragma unroll
    for (int rt = 0; rt < 4; ++rt)
#pragma unroll
      for (int cf = 0; cf < 4; ++cf) acc[rt][cf] = z;
    for (int kt = 0; kt < 8; ++kt) {
      short8 a[4], b[4];
#pragma unroll
      for (int rt = 0; rt < 4; ++rt) a[rt] = lds_afrag(sh, 512, rt, kt, lane);
#pragma unroll
      for (int cf = 0; cf < 4; ++cf)
        b[cf] = ldg_bfrag(W0f, 32, (wv << 2) + cf, (s << 3) + kt, lane);
#pragma unroll
      for (int rt = 0; rt < 4; ++rt)
#pragma unroll
        for (int cf = 0; cf < 4; ++cf)
          acc[rt][cf] = __builtin_amdgcn_mfma_f32_16x16x32_bf16(a[rt], b[cf], acc[rt][cf], 0, 0, 0);
    }
#pragma unroll
    for (int rt = 0; rt < 4; ++rt)
#pragma unroll
      for (int cf = 0; cf < 4; ++cf) {
        int col = (wv << 6) + (cf << 4) + (lane & 15);
#pragma unroll
        for (int i = 0; i < 4; ++i) {
          int row = rt * 16 + ((lane >> 4) << 2) + i;
          int ga = r0 + row;
          if (ga < n_atoms) p[((size_t)ga * 4 + s) * 512 + col] = f2bf(acc[rt][cf][i]);
        }
      }
  }
}

struct P2 {
  const int* idxs;
  const short* p;
  const short *W1, *W2, *W3, *Wt0, *Wt1, *Wc0;
  const float *bs0, *bs1, *bs2, *bs3, *bt0, *bt1, *bt2, *bc0, *bc1;
  const float *Wt2, *Wc1;
  float* out;
  int n_tors;
};

// dual-chain residual layer with B-prefetch; if SYM, epilogue writes hf+hr -> hf only
template <bool SYM>
__device__ __forceinline__ void layer_dual2(char* hf, char* hr,
                                            const short* __restrict__ W,
                                            const float* __restrict__ bias,
                                            int wv, int lane) {
  f32x4 accf[4][4], accr[4][4];
  const f32x4 z = {0.f, 0.f, 0.f, 0.f};
#pragma unroll
  for (int rt = 0; rt < 4; ++rt)
#pragma unroll
    for (int cf = 0; cf < 4; ++cf) { accf[rt][cf] = z; accr[rt][cf] = z; }
  short8 bC[4], bN[4];
#pragma unroll
  for (int cf = 0; cf < 4; ++cf) bC[cf] = ldg_bfrag(W, 16, (wv << 2) + cf, 0, lane);
#pragma unroll 1
  for (int kt = 0; kt < 16; ++kt) {
#pragma unroll
    for (int cf = 0; cf < 4; ++cf)
      bN[cf] = ldg_bfrag(W, 16, (wv << 2) + cf, (kt + 1) & 15, lane);
    short8 af[4], ar[4];
#pragma unroll
    for (int rt = 0; rt < 4; ++rt) {
      af[rt] = lds_afrag(hf, 1024, rt, kt, lane);
      ar[rt] = lds_afrag(hr, 1024, rt, kt, lane);
    }
#pragma unroll
    for (int rt = 0; rt < 4; ++rt)
#pragma unroll
      for (int cf = 0; cf < 4; ++cf) {
        accf[rt][cf] = __builtin_amdgcn_mfma_f32_16x16x32_bf16(af[rt], bC[cf], accf[rt][cf], 0, 0, 0);
        accr[rt][cf] = __builtin_amdgcn_mfma_f32_16x16x32_bf16(ar[rt], bC[cf], accr[rt][cf], 0, 0, 0);
      }
#pragma unroll
    for (int cf = 0; cf < 4; ++cf) bC[cf] = bN[cf];
  }
  float bcol[4];
#pragma unroll
  for (int cf = 0; cf < 4; ++cf) bcol[cf] = bias[(wv << 6) + (cf << 4) + (lane & 15)];
  __syncthreads();
#pragma unroll
  for (int rt = 0; rt < 4; ++rt)
#pragma unroll
    for (int cf = 0; cf < 4; ++cf) {
      int col = (wv << 6) + (cf << 4) + (lane & 15);
#pragma unroll
      for (int i = 0; i < 4; ++i) {
        int row = rt * 16 + ((lane >> 4) << 2) + i;
        size_t off = (size_t)row * 1024 + ((col * 2) ^ ((row & 7) << 4));
        short* pf = (short*)(hf + off);
        short* pr = (short*)(hr + off);
        float nf = bf2f(*pf) + elu_f(accf[rt][cf][i] + bcol[cf]);
        float nr = bf2f(*pr) + elu_f(accr[rt][cf][i] + bcol[cf]);
        if (SYM) {
          *pf = f2bf(nf + nr);
        } else {
          *pf = f2bf(nf);
          *pr = f2bf(nr);
        }
      }
    }
  __syncthreads();
}

// single-chain: out = res + elu(in @ W + b); out may alias in/res
__device__ __forceinline__ void layer_single2(const char* in,
                                              const short* __restrict__ W,
                                              const float* __restrict__ bias,
                                              const char* res, char* out,
                                              int wv, int lane) {
  f32x4 acc[4][4];
  const f32x4 z = {0.f, 0.f, 0.f, 0.f};
#pragma unroll
  for (int rt = 0; rt < 4; ++rt)
#pragma unroll
    for (int cf = 0; cf < 4; ++cf) acc[rt][cf] = z;
  short8 bC[4], bN[4];
#pragma unroll
  for (int cf = 0; cf < 4; ++cf) bC[cf] = ldg_bfrag(W, 16, (wv << 2) + cf, 0, lane);
#pragma unroll 1
  for (int kt = 0; kt < 16; ++kt) {
#pragma unroll
    for (int cf = 0; cf < 4; ++cf)
      bN[cf] = ldg_bfrag(W, 16, (wv << 2) + cf, (kt + 1) & 15, lane);
    short8 a[4];
#pragma unroll
    for (int rt = 0; rt < 4; ++rt) a[rt] = lds_afrag(in, 1024, rt, kt, lane);
#pragma unroll
    for (int rt = 0; rt < 4; ++rt)
#pragma unroll
      for (int cf = 0; cf < 4; ++cf)
        acc[rt][cf] = __builtin_amdgcn_mfma_f32_16x16x32_bf16(a[rt], bC[cf], acc[rt][cf], 0, 0, 0);
#pragma unroll
    for (int cf = 0; cf < 4; ++cf) bC[cf] = bN[cf];
  }
  float bcol[4];
#pragma unroll
  for (int cf = 0; cf < 4; ++cf) bcol[cf] = bias[(wv << 6) + (cf << 4) + (lane & 15)];
  __syncthreads();
#pragma unroll
  for (int rt = 0; rt < 4; ++rt)
#pragma unroll
    for (int cf = 0; cf < 4; ++cf) {
      int col = (wv << 6) + (cf << 4) + (lane & 15);
#pragma unroll
      for (int i = 0; i < 4; ++i) {
        int row = rt * 16 + ((lane >> 4) << 2) + i;
        size_t off = (size_t)row * 1024 + ((col * 2) ^ ((row & 7) << 4));
        float v = elu_f(acc[rt][cf][i] + bcol[cf]) + bf2f(*(const short*)(res + off));
        *(short*)(out + off) = f2bf(v);
      }
    }
  __syncthreads();
}

__global__ __launch_bounds__(NTHREADS, 2) void fused2(P2 p) {
  __shared__ char smem[BM * 2048];     // sA | sB (64 KB each)
  __shared__ int sIdx[BM * 4];
  __shared__ float sSmall[BM * 12];
  char* sA = smem;
  char* sB = smem + BM * 1024;
  const int tid = threadIdx.x;
  const int lane = tid & 63;
  const int wv = tid >> 6;
  const int r0 = blockIdx.x * BM;

  for (int i = tid; i < BM * 4; i += NTHREADS) {
    int grow = r0 + (i >> 2);
    sIdx[i] = (grow < p.n_tors) ? p.idxs[(size_t)grow * 4 + (i & 3)] : 0;
  }
  __syncthreads();

  // ---- layer0 via gathered per-atom partials ----
  for (int i = tid; i < BM * 64; i += NTHREADS) {
    int row = i >> 6, c0 = (i & 63) << 3;   // wave handles one row: coalesced 16B
    float sf[8], sr[8];
#pragma unroll
    for (int e = 0; e < 8; ++e) { sf[e] = p.bs0[c0 + e]; sr[e] = sf[e]; }
#pragma unroll
    for (int j = 0; j < 4; ++j) {
      int a = sIdx[row * 4 + j];
      short8 vf = *(const short8*)(p.p + ((size_t)a * 4 + j) * 512 + c0);
      short8 vr = *(const short8*)(p.p + ((size_t)a * 4 + (3 - j)) * 512 + c0);
#pragma unroll
      for (int e = 0; e < 8; ++e) { sf[e] += bf2f(vf[e]); sr[e] += bf2f(vr[e]); }
    }
    short8 of, orv;
#pragma unroll
    for (int e = 0; e < 8; ++e) { of[e] = f2bf(elu_f(sf[e])); orv[e] = f2bf(elu_f(sr[e])); }
    size_t off = (size_t)row * 1024 + ((c0 * 2) ^ ((row & 7) << 4));
    *(short8*)(sA + off) = of;
    *(short8*)(sB + off) = orv;
  }
  __syncthreads();

  layer_dual2<false>(sA, sB, p.W1, p.bs1, wv, lane);
  layer_dual2<false>(sA, sB, p.W2, p.bs2, wv, lane);
  layer_dual2<true >(sA, sB, p.W3, p.bs3, wv, lane);   // writes sym -> sA

  layer_single2(sA, p.Wt0, p.bt0, sA, sB, wv, lane);   // t0 = sym + elu(sym@Wt0)
  layer_single2(sB, p.Wt1, p.bt1, sB, sB, wv, lane);   // t1 = t0 + elu(t0@Wt1)
  layer_single2(sA, p.Wc0, p.bc0, sA, sA, wv, lane);   // c  = sym + elu(sym@Wc0)

  for (int idx = tid; idx < BM * 12; idx += NTHREADS) {
    int row = idx / 12, jj = idx - row * 12;
    int j = (jj < 6) ? jj : jj - 6;
    const char* src = (jj < 6) ? sB : sA;
    const float* W = (jj < 6) ? p.Wt2 : p.Wc1;
    float acc = (jj < 6) ? p.bt2[j] : p.bc1[j];
    for (int c0 = 0; c0 < 512; c0 += 8) {
      short8 v = *(const short8*)(src + (size_t)row * 1024 + ((c0 * 2) ^ ((row & 7) << 4)));
#pragma unroll
      for (int e = 0; e < 8; ++e) acc += bf2f(v[e]) * W[(c0 + e) * 6 + j];
    }
    sSmall[row * 12 + jj] = acc;
  }
  __syncthreads();
  for (int idx = tid; idx < BM * 6; idx += NTHREADS) {
    int row = idx / 6, j = idx - row * 6;
    int grow = r0 + row;
    if (grow < p.n_tors) {
      float score = sSmall[row * 12 + 6 + j];
      float coeff = sSmall[row * 12 + j];
      p.out[(size_t)grow * 6 + j] = score;
      p.out[(size_t)p.n_tors * 6 + (size_t)grow * 6 + j] =
          coeff * 0.001f * (1.0f / (1.0f + __expf(-score)));
    }
  }
}

// ================= LEGACY PATH (round-1, fallback if ws too small) =================

struct Params {
  const float* h;
  const int* idxs;
  const short *W0f, *W0r, *W1, *W2, *W3, *Wt0, *Wt1, *Wc0;
  const float *bs0, *bs1, *bs2, *bs3, *bt0, *bt1, *bt2, *bc0, *bc1;
  const float *Wt2, *Wc1;
  float* out;
  int n_tors;
};

__device__ __forceinline__ void layer_dual(char* hf, char* hr,
                                           const short* __restrict__ W,
                                           const float* __restrict__ bias,
                                           int wv, int lane) {
  f32x4 accf[4][4], accr[4][4];
  const f32x4 z = {0.f, 0.f, 0.f, 0.f};
#pragma unroll
  for (int rt = 0; rt < 4; ++rt)
#pragma unroll
    for (int cf = 0; cf < 4; ++cf) { accf[rt][cf] = z; accr[rt][cf] = z; }
  for (int kt = 0; kt < 16; ++kt) {
    short8 af[4], ar[4], b[4];
#pragma unroll
    for (int rt = 0; rt < 4; ++rt) {
      af[rt] = lds_afrag(hf, 1024, rt, kt, lane);
      ar[rt] = lds_afrag(hr, 1024, rt, kt, lane);
    }
#pragma unroll
    for (int cf = 0; cf < 4; ++cf) b[cf] = ldg_bfrag(W, 16, (wv << 2) + cf, kt, lane);
#pragma unroll
    for (int rt = 0; rt < 4; ++rt)
#pragma unroll
      for (int cf = 0; cf < 4; ++cf) {
        accf[rt][cf] = __builtin_amdgcn_mfma_f32_16x16x32_bf16(af[rt], b[cf], accf[rt][cf], 0, 0, 0);
        accr[rt][cf] = __builtin_amdgcn_mfma_f32_16x16x32_bf16(ar[rt], b[cf], accr[rt][cf], 0, 0, 0);
      }
  }
  float bcol[4];
#pragma unroll
  for (int cf = 0; cf < 4; ++cf) bcol[cf] = bias[(wv << 6) + (cf << 4) + (lane & 15)];
  __syncthreads();
#pragma unroll
  for (int rt = 0; rt < 4; ++rt)
#pragma unroll
    for (int cf = 0; cf < 4; ++cf) {
      int col = (wv << 6) + (cf << 4) + (lane & 15);
#pragma unroll
      for (int i = 0; i < 4; ++i) {
        int row = rt * 16 + ((lane >> 4) << 2) + i;
        size_t off = (size_t)row * 1024 + ((col * 2) ^ ((row & 7) << 4));
        short* pf = (short*)(hf + off);
        short* pr = (short*)(hr + off);
        *pf = f2bf(bf2f(*pf) + elu_f(accf[rt][cf][i] + bcol[cf]));
        *pr = f2bf(bf2f(*pr) + elu_f(accr[rt][cf][i] + bcol[cf]));
      }
    }
  __syncthreads();
}

__device__ __forceinline__ void layer_single(const char* in,
                                             const short* __restrict__ W,
                                             const float* __restrict__ bias,
                                             const char* res, char* out,
                                             int wv, int lane) {
  f32x4 acc[4][4];
  const f32x4 z = {0.f, 0.f, 0.f, 0.f};
#pragma unroll
  for (int rt = 0; rt < 4; ++rt)
#pragma unroll
    for (int cf = 0; cf < 4; ++cf) acc[rt][cf] = z;
  for (int kt = 0; kt < 16; ++kt) {
    short8 a[4], b[4];
#pragma unroll
    for (int rt = 0; rt < 4; ++rt) a[rt] = lds_afrag(in, 1024, rt, kt, lane);
#pragma unroll
    for (int cf = 0; cf < 4; ++cf) b[cf] = ldg_bfrag(W, 16, (wv << 2) + cf, kt, lane);
#pragma unroll
    for (int rt = 0; rt < 4; ++rt)
#pragma unroll
      for (int cf = 0; cf < 4; ++cf)
        acc[rt][cf] = __builtin_amdgcn_mfma_f32_16x16x32_bf16(a[rt], b[cf], acc[rt][cf], 0, 0, 0);
  }
  float bcol[4];
#pragma unroll
  for (int cf = 0; cf < 4; ++cf) bcol[cf] = bias[(wv << 6) + (cf << 4) + (lane & 15)];
  __syncthreads();
#pragma unroll
  for (int rt = 0; rt < 4; ++rt)
#pragma unroll
    for (int cf = 0; cf < 4; ++cf) {
      int col = (wv << 6) + (cf << 4) + (lane & 15);
#pragma unroll
      for (int i = 0; i < 4; ++i) {
        int row = rt * 16 + ((lane >> 4) << 2) + i;
        size_t off = (size_t)row * 1024 + ((col * 2) ^ ((row & 7) << 4));
        float v = elu_f(acc[rt][cf][i] + bcol[cf]) + bf2f(*(const short*)(res + off));
        *(short*)(out + off) = f2bf(v);
      }
    }
  __syncthreads();
}

__global__ __launch_bounds__(NTHREADS) void fused(Params p) {
  __shared__ char smem[BM * 2048];
  __shared__ float sSmall[BM * 12];
  char* sA = smem;
  char* sB = smem + BM * 1024;
  const int tid = threadIdx.x;
  const int lane = tid & 63;
  const int wv = tid >> 6;
  const int r0 = blockIdx.x * BM;

  for (int c = tid; c < BM * 128; c += NTHREADS) {
    int row = c >> 7;
    int col0 = (c & 127) << 3;
    int grow = r0 + row;
    short8 o;
    if (grow < p.n_tors) {
      int f = col0 >> 8;
      int cin = col0 & 255;
      int a = p.idxs[(size_t)grow * 4 + f];
      const float4* s4 = (const float4*)(p.h + (size_t)a * 256 + cin);
      float4 v0 = s4[0], v1 = s4[1];
      o[0] = f2bf(v0.x); o[1] = f2bf(v0.y); o[2] = f2bf(v0.z); o[3] = f2bf(v0.w);
      o[4] = f2bf(v1.x); o[5] = f2bf(v1.y); o[6] = f2bf(v1.z); o[7] = f2bf(v1.w);
    } else {
#pragma unroll
      for (int e = 0; e < 8; ++e) o[e] = 0;
    }
    *(short8*)(smem + (size_t)row * 2048 + ((col0 * 2) ^ ((row & 7) << 4))) = o;
  }
  __syncthreads();

  {
    f32x4 accf[4][4], accr[4][4];
    const f32x4 z = {0.f, 0.f, 0.f, 0.f};
#pragma unroll
    for (int rt = 0; rt < 4; ++rt)
#pragma unroll
      for (int cf = 0; cf < 4; ++cf) { accf[rt][cf] = z; accr[rt][cf] = z; }
    for (int kt = 0; kt < 32; ++kt) {
      short8 a[4], bfw[4], brw[4];
#pragma unroll
      for (int rt = 0; rt < 4; ++rt) a[rt] = lds_afrag(smem, 2048, rt, kt, lane);
#pragma unroll
      for (int cf = 0; cf < 4; ++cf) {
        bfw[cf] = ldg_bfrag(p.W0f, 32, (wv << 2) + cf, kt, lane);
        brw[cf] = ldg_bfrag(p.W0r, 32, (wv << 2) + cf, kt, lane);
      }
#pragma unroll
      for (int rt = 0; rt < 4; ++rt)
#pragma unroll
        for (int cf = 0; cf < 4; ++cf) {
          accf[rt][cf] = __builtin_amdgcn_mfma_f32_16x16x32_bf16(a[rt], bfw[cf], accf[rt][cf], 0, 0, 0);
          accr[rt][cf] = __builtin_amdgcn_mfma_f32_16x16x32_bf16(a[rt], brw[cf], accr[rt][cf], 0, 0, 0);
        }
    }
    float bcol[4];
#pragma unroll
    for (int cf = 0; cf < 4; ++cf) bcol[cf] = p.bs0[(wv << 6) + (cf << 4) + (lane & 15)];
    __syncthreads();
#pragma unroll
    for (int rt = 0; rt < 4; ++rt)
#pragma unroll
      for (int cf = 0; cf < 4; ++cf) {
        int col = (wv << 6) + (cf << 4) + (lane & 15);
#pragma unroll
        for (int i = 0; i < 4; ++i) {
          int row = rt * 16 + ((lane >> 4) << 2) + i;
          size_t off = (size_t)row * 1024 + ((col * 2) ^ ((row & 7) << 4));
          *(short*)(sA + off) = f2bf(elu_f(accf[rt][cf][i] + bcol[cf]));
          *(short*)(sB + off) = f2bf(elu_f(accr[rt][cf][i] + bcol[cf]));
        }
      }
    __syncthreads();
  }

  layer_dual(sA, sB, p.W1, p.bs1, wv, lane);
  layer_dual(sA, sB, p.W2, p.bs2, wv, lane);
  layer_dual(sA, sB, p.W3, p.bs3, wv, lane);

  for (int c = tid; c < BM * 64; c += NTHREADS) {
    int row = c >> 6;
    int col0 = (c & 63) << 3;
    size_t off = (size_t)row * 1024 + ((col0 * 2) ^ ((row & 7) << 4));
    short8 xa = *(short8*)(sA + off);
    short8 xb = *(short8*)(sB + off);
    short8 o;
#pragma unroll
    for (int e = 0; e < 8; ++e) o[e] = f2bf(bf2f(xa[e]) + bf2f(xb[e]));
    *(short8*)(sA + off) = o;
  }
  __syncthreads();

  layer_single(sA, p.Wt0, p.bt0, sA, sB, wv, lane);
  layer_single(sB, p.Wt1, p.bt1, sB, sB, wv, lane);
  layer_single(sA, p.Wc0, p.bc0, sA, sA, wv, lane);

  for (int idx = tid; idx < BM * 12; idx += NTHREADS) {
    int row = idx / 12, jj = idx - row * 12;
    int j = (jj < 6) ? jj : jj - 6;
    const char* src = (jj < 6) ? sB : sA;
    const float* W = (jj < 6) ? p.Wt2 : p.Wc1;
    float acc = (jj < 6) ? p.bt2[j] : p.bc1[j];
    for (int c0 = 0; c0 < 512; c0 += 8) {
      short8 v = *(const short8*)(src + (size_t)row * 1024 + ((c0 * 2) ^ ((row & 7) << 4)));
#pragma unroll
      for (int e = 0; e < 8; ++e) acc += bf2f(v[e]) * W[(c0 + e) * 6 + j];
    }
    sSmall[row * 12 + jj] = acc;
  }
  __syncthreads();
  for (int idx = tid; idx < BM * 6; idx += NTHREADS) {
    int row = idx / 6, j = idx - row * 6;
    int grow = r0 + row;
    if (grow < p.n_tors) {
      float score = sSmall[row * 12 + 6 + j];
      float coeff = sSmall[row * 12 + j];
      p.out[(size_t)grow * 6 + j] = score;
      p.out[(size_t)p.n_tors * 6 + (size_t)grow * 6 + j] =
          coeff * 0.001f * (1.0f / (1.0f + __expf(-score)));
    }
  }
}

// ================= LAUNCH =================

extern "C" void kernel_launch(void* const* d_in, const int* in_sizes, int n_in,
                              void* d_out, int out_size, void* d_ws, size_t ws_size,
                              hipStream_t stream) {
  const float* h   = (const float*)d_in[0];
  const int* idxs  = (const int*)d_in[1];
  const float* Ws0 = (const float*)d_in[2];
  const float* bs0 = (const float*)d_in[3];
  const float* Ws1 = (const float*)d_in[4];
  const float* bs1 = (const float*)d_in[5];
  const float* Ws2 = (const float*)d_in[6];
  const float* bs2 = (const float*)d_in[7];
  const float* Ws3 = (const float*)d_in[8];
  const float* bs3 = (const float*)d_in[9];
  const float* Wt0 = (const float*)d_in[10];
  const float* bt0 = (const float*)d_in[11];
  const float* Wt1 = (const float*)d_in[12];
  const float* bt1 = (const float*)d_in[13];
  const float* Wt2 = (const float*)d_in[14];
  const float* bt2 = (const float*)d_in[15];
  const float* Wc0 = (const float*)d_in[16];
  const float* bc0 = (const float*)d_in[17];
  const float* Wc1 = (const float*)d_in[18];
  const float* bc1 = (const float*)d_in[19];
  int n_tors = in_sizes[1] / 4;
  int n_atoms = in_sizes[0] / 256;

  auto pk = [&](const float* s, short* dmem, int K, int N, int rev) {
    int tiles = (N >> 4) * (K >> 5);
    pack_w<<<dim3((tiles + 3) / 4), dim3(256), 0, stream>>>(s, dmem, K, N, rev);
  };

  size_t pElems = (size_t)n_atoms * 4 * 512;
  size_t needNew = (pElems + 524288 + 6 * 262144) * sizeof(short);

  if (ws_size >= needNew) {
    // ---- new path: per-atom layer0 precompute ----
    short* ws = (short*)d_ws;
    short* pT  = ws;
    short* W0f = ws + pElems;
    short* W1  = W0f + 524288;
    short* W2  = W1 + 262144;
    short* W3  = W2 + 262144;
    short* Wt0c = W3 + 262144;
    short* Wt1c = Wt0c + 262144;
    short* Wc0c = Wt1c + 262144;

    pk(Ws0, W0f, 1024, 512, 0);
    pk(Ws1, W1, 512, 512, 0);
    pk(Ws2, W2, 512, 512, 0);
    pk(Ws3, W3, 512, 512, 0);
    pk(Wt0, Wt0c, 512, 512, 0);
    pk(Wt1, Wt1c, 512, 512, 0);
    pk(Wc0, Wc0c, 512, 512, 0);

    atom_pre<<<dim3((n_atoms + BM - 1) / BM), dim3(NTHREADS), 0, stream>>>(h, W0f, pT, n_atoms);

    P2 p;
    p.idxs = idxs; p.p = pT;
    p.W1 = W1; p.W2 = W2; p.W3 = W3;
    p.Wt0 = Wt0c; p.Wt1 = Wt1c; p.Wc0 = Wc0c;
    p.bs0 = bs0; p.bs1 = bs1; p.bs2 = bs2; p.bs3 = bs3;
    p.bt0 = bt0; p.bt1 = bt1; p.bt2 = bt2; p.bc0 = bc0; p.bc1 = bc1;
    p.Wt2 = Wt2; p.Wc1 = Wc1;
    p.out = (float*)d_out; p.n_tors = n_tors;

    fused2<<<dim3((n_tors + BM - 1) / BM), dim3(NTHREADS), 0, stream>>>(p);
  } else {
    // ---- legacy path ----
    short* ws = (short*)d_ws;
    short* W0f = ws;
    short* W0r = ws + 524288;
    short* W1  = ws + 1048576;
    short* W2  = W1 + 262144;
    short* W3  = W2 + 262144;
    short* Wt0c = W3 + 262144;
    short* Wt1c = Wt0c + 262144;
    short* Wc0c = Wt1c + 262144;

    pk(Ws0, W0f, 1024, 512, 0);
    pk(Ws0, W0r, 1024, 512, 1);
    pk(Ws1, W1, 512, 512, 0);
    pk(Ws2, W2, 512, 512, 0);
    pk(Ws3, W3, 512, 512, 0);
    pk(Wt0, Wt0c, 512, 512, 0);
    pk(Wt1, Wt1c, 512, 512, 0);
    pk(Wc0, Wc0c, 512, 512, 0);

    Params p;
    p.h = h; p.idxs = idxs;
    p.W0f = W0f; p.W0r = W0r; p.W1 = W1; p.W2 = W2; p.W3 = W3;
    p.Wt0 = Wt0c; p.Wt1 = Wt1c; p.Wc0 = Wc0c;
    p.bs0 = bs0; p.bs1 = bs1; p.bs2 = bs2; p.bs3 = bs3;
    p.bt0 = bt0; p.bt1 = bt1; p.bt2 = bt2; p.bc0 = bc0; p.bc1 = bc1;
    p.Wt2 = Wt2; p.Wc1 = Wc1;
    p.out = (float*)d_out; p.n_tors = n_tors;

    fused<<<dim3((n_tors + BM - 1) / BM), dim3(NTHREADS), 0, stream>>>(p);
  }
}

// Round 3
// 3191.186 us; speedup vs baseline: 1.6347x; 1.0764x over previous
//
#include <hip/hip_runtime.h>

#define BM 64
#define NTHREADS 512   // atom_pre / legacy
#define NT2 1024       // fused2: 16 waves

typedef __attribute__((ext_vector_type(8))) short short8;
typedef __attribute__((ext_vector_type(4))) float f32x4;

__device__ __forceinline__ short f2bf(float f) {
  unsigned u = __builtin_bit_cast(unsigned, f);
  u += 0x7FFFu + ((u >> 16) & 1u);   // RNE
  return (short)(u >> 16);
}
__device__ __forceinline__ float bf2f(short s) {
  unsigned u = ((unsigned)(unsigned short)s) << 16;
  return __builtin_bit_cast(float, u);
}
__device__ __forceinline__ float elu_f(float v) {
  return v > 0.f ? v : (__expf(v) - 1.f);
}

// ---- pack f32 [K][N] weight into bf16 MFMA-fragment order ----
__global__ __launch_bounds__(256) void pack_w(const float* __restrict__ src,
                                              short* __restrict__ dst,
                                              int K, int N, int rev) {
  int tile = blockIdx.x * 4 + (threadIdx.x >> 6);
  int lane = threadIdx.x & 63;
  int ktiles = K >> 5;
  int tot = (N >> 4) * ktiles;
  if (tile >= tot) return;
  int nt = tile / ktiles, kt = tile - nt * ktiles;
  int col = (nt << 4) + (lane & 15);
  int k0 = (kt << 5) + ((lane >> 4) << 3);
  short8 o;
#pragma unroll
  for (int j = 0; j < 8; ++j) {
    int kr = k0 + j;
    if (rev) kr = ((3 - (kr >> 8)) << 8) | (kr & 255);
    o[j] = f2bf(src[(size_t)kr * N + col]);
  }
  *(short8*)(dst + (size_t)tile * 512 + lane * 8) = o;
}

__device__ __forceinline__ short8 lds_afrag(const char* base, int stride, int rt,
                                            int kt, int lane) {
  int row = rt * 16 + (lane & 15);
  int boff = (kt << 6) + ((lane >> 4) << 4);
  return *(const short8*)(base + row * stride + (boff ^ ((row & 7) << 4)));
}
__device__ __forceinline__ short8 ldg_bfrag(const short* W, int ktiles, int ct,
                                            int kt, int lane) {
  return *(const short8*)(W + ((size_t)(ct * ktiles + kt) << 9) + (lane << 3));
}

// ================= atom precompute =================
// p[a][s][c] = h_a(256) @ Ws0[256s:256s+256, :]   (bf16, [n_atoms][4][512])
__global__ __launch_bounds__(NTHREADS) void atom_pre(const float* __restrict__ h,
                                                     const short* __restrict__ W0f,
                                                     short* __restrict__ p,
                                                     int n_atoms) {
  __shared__ char sh[BM * 512];
  const int tid = threadIdx.x, lane = tid & 63, wv = tid >> 6;
  const int r0 = blockIdx.x * BM;
  for (int i = tid; i < BM * 32; i += NTHREADS) {
    int row = i >> 5, c0 = (i & 31) << 3;
    int ga = r0 + row;
    short8 o;
    if (ga < n_atoms) {
      const float4* s4 = (const float4*)(h + (size_t)ga * 256 + c0);
      float4 v0 = s4[0], v1 = s4[1];
      o[0] = f2bf(v0.x); o[1] = f2bf(v0.y); o[2] = f2bf(v0.z); o[3] = f2bf(v0.w);
      o[4] = f2bf(v1.x); o[5] = f2bf(v1.y); o[6] = f2bf(v1.z); o[7] = f2bf(v1.w);
    } else {
#pragma unroll
      for (int e = 0; e < 8; ++e) o[e] = 0;
    }
    *(short8*)(sh + row * 512 + ((c0 * 2) ^ ((row & 7) << 4))) = o;
  }
  __syncthreads();
#pragma unroll 1
  for (int s = 0; s < 4; ++s) {
    f32x4 acc[4][4];
    const f32x4 z = {0.f, 0.f, 0.f, 0.f};
#pragma unroll
    for (int rt = 0; rt < 4; ++rt)
#pragma unroll
      for (int cf = 0; cf < 4; ++cf) acc[rt][cf] = z;
    for (int kt = 0; kt < 8; ++kt) {
      short8 a[4], b[4];
#pragma unroll
      for (int rt = 0; rt < 4; ++rt) a[rt] = lds_afrag(sh, 512, rt, kt, lane);
#pragma unroll
      for (int cf = 0; cf < 4; ++cf)
        b[cf] = ldg_bfrag(W0f, 32, (wv << 2) + cf, (s << 3) + kt, lane);
#pragma unroll
      for (int rt = 0; rt < 4; ++rt)
#pragma unroll
        for (int cf = 0; cf < 4; ++cf)
          acc[rt][cf] = __builtin_amdgcn_mfma_f32_16x16x32_bf16(a[rt], b[cf], acc[rt][cf], 0, 0, 0);
    }
#pragma unroll
    for (int rt = 0; rt < 4; ++rt)
#pragma unroll
      for (int cf = 0; cf < 4; ++cf) {
        int col = (wv << 6) + (cf << 4) + (lane & 15);
#pragma unroll
        for (int i = 0; i < 4; ++i) {
          int row = rt * 16 + ((lane >> 4) << 2) + i;
          int ga = r0 + row;
          if (ga < n_atoms) p[((size_t)ga * 4 + s) * 512 + col] = f2bf(acc[rt][cf][i]);
        }
      }
  }
}

struct P2 {
  const int* idxs;
  const short* p;
  const short *W1, *W2, *W3, *Wt0, *Wt1, *Wc0;
  const float *bs0, *bs1, *bs2, *bs3, *bt0, *bt1, *bt2, *bc0, *bc1;
  const float *Wt2, *Wc1;
  float* out;
  int n_tors;
};

// ---- 16-wave variants: wave owns 32 cols (2 cf tiles) ----
template <bool SYM>
__device__ __forceinline__ void layer_dual3(char* hf, char* hr,
                                            const short* __restrict__ W,
                                            const float* __restrict__ bias,
                                            int wv, int lane) {
  f32x4 accf[4][2], accr[4][2];
  const f32x4 z = {0.f, 0.f, 0.f, 0.f};
#pragma unroll
  for (int rt = 0; rt < 4; ++rt)
#pragma unroll
    for (int cf = 0; cf < 2; ++cf) { accf[rt][cf] = z; accr[rt][cf] = z; }
  short8 bC[2], bN[2];
#pragma unroll
  for (int cf = 0; cf < 2; ++cf) bC[cf] = ldg_bfrag(W, 16, (wv << 1) + cf, 0, lane);
#pragma unroll 1
  for (int kt = 0; kt < 16; ++kt) {
#pragma unroll
    for (int cf = 0; cf < 2; ++cf)
      bN[cf] = ldg_bfrag(W, 16, (wv << 1) + cf, (kt + 1) & 15, lane);
    short8 af[4], ar[4];
#pragma unroll
    for (int rt = 0; rt < 4; ++rt) {
      af[rt] = lds_afrag(hf, 1024, rt, kt, lane);
      ar[rt] = lds_afrag(hr, 1024, rt, kt, lane);
    }
#pragma unroll
    for (int rt = 0; rt < 4; ++rt)
#pragma unroll
      for (int cf = 0; cf < 2; ++cf) {
        accf[rt][cf] = __builtin_amdgcn_mfma_f32_16x16x32_bf16(af[rt], bC[cf], accf[rt][cf], 0, 0, 0);
        accr[rt][cf] = __builtin_amdgcn_mfma_f32_16x16x32_bf16(ar[rt], bC[cf], accr[rt][cf], 0, 0, 0);
      }
#pragma unroll
    for (int cf = 0; cf < 2; ++cf) bC[cf] = bN[cf];
  }
  float bcol[2];
#pragma unroll
  for (int cf = 0; cf < 2; ++cf) bcol[cf] = bias[(wv << 5) + (cf << 4) + (lane & 15)];
  __syncthreads();
#pragma unroll
  for (int rt = 0; rt < 4; ++rt)
#pragma unroll
    for (int cf = 0; cf < 2; ++cf) {
      int col = (wv << 5) + (cf << 4) + (lane & 15);
#pragma unroll
      for (int i = 0; i < 4; ++i) {
        int row = rt * 16 + ((lane >> 4) << 2) + i;
        size_t off = (size_t)row * 1024 + ((col * 2) ^ ((row & 7) << 4));
        short* pf = (short*)(hf + off);
        short* pr = (short*)(hr + off);
        float nf = bf2f(*pf) + elu_f(accf[rt][cf][i] + bcol[cf]);
        float nr = bf2f(*pr) + elu_f(accr[rt][cf][i] + bcol[cf]);
        if (SYM) {
          *pf = f2bf(nf + nr);
        } else {
          *pf = f2bf(nf);
          *pr = f2bf(nr);
        }
      }
    }
  __syncthreads();
}

__device__ __forceinline__ void layer_single3(const char* in,
                                              const short* __restrict__ W,
                                              const float* __restrict__ bias,
                                              const char* res, char* out,
                                              int wv, int lane) {
  f32x4 acc[4][2];
  const f32x4 z = {0.f, 0.f, 0.f, 0.f};
#pragma unroll
  for (int rt = 0; rt < 4; ++rt)
#pragma unroll
    for (int cf = 0; cf < 2; ++cf) acc[rt][cf] = z;
  short8 bC[2], bN[2];
#pragma unroll
  for (int cf = 0; cf < 2; ++cf) bC[cf] = ldg_bfrag(W, 16, (wv << 1) + cf, 0, lane);
#pragma unroll 1
  for (int kt = 0; kt < 16; ++kt) {
#pragma unroll
    for (int cf = 0; cf < 2; ++cf)
      bN[cf] = ldg_bfrag(W, 16, (wv << 1) + cf, (kt + 1) & 15, lane);
    short8 a[4];
#pragma unroll
    for (int rt = 0; rt < 4; ++rt) a[rt] = lds_afrag(in, 1024, rt, kt, lane);
#pragma unroll
    for (int rt = 0; rt < 4; ++rt)
#pragma unroll
      for (int cf = 0; cf < 2; ++cf)
        acc[rt][cf] = __builtin_amdgcn_mfma_f32_16x16x32_bf16(a[rt], bC[cf], acc[rt][cf], 0, 0, 0);
#pragma unroll
    for (int cf = 0; cf < 2; ++cf) bC[cf] = bN[cf];
  }
  float bcol[2];
#pragma unroll
  for (int cf = 0; cf < 2; ++cf) bcol[cf] = bias[(wv << 5) + (cf << 4) + (lane & 15)];
  __syncthreads();
#pragma unroll
  for (int rt = 0; rt < 4; ++rt)
#pragma unroll
    for (int cf = 0; cf < 2; ++cf) {
      int col = (wv << 5) + (cf << 4) + (lane & 15);
#pragma unroll
      for (int i = 0; i < 4; ++i) {
        int row = rt * 16 + ((lane >> 4) << 2) + i;
        size_t off = (size_t)row * 1024 + ((col * 2) ^ ((row & 7) << 4));
        float v = elu_f(acc[rt][cf][i] + bcol[cf]) + bf2f(*(const short*)(res + off));
        *(short*)(out + off) = f2bf(v);
      }
    }
  __syncthreads();
}

__global__ __launch_bounds__(NT2) void fused2(P2 p) {
  __shared__ char smem[BM * 2048];     // sA | sB (64 KB each)
  __shared__ int sIdx[BM * 4];
  __shared__ float sSmall[BM * 12];
  char* sA = smem;
  char* sB = smem + BM * 1024;
  const int tid = threadIdx.x;
  const int lane = tid & 63;
  const int wv = tid >> 6;             // 0..15
  const int r0 = blockIdx.x * BM;

  for (int i = tid; i < BM * 4; i += NT2) {
    int grow = r0 + (i >> 2);
    sIdx[i] = (grow < p.n_tors) ? p.idxs[(size_t)grow * 4 + (i & 3)] : 0;
  }
  __syncthreads();

  // ---- layer0 via gathered per-atom partials ----
  for (int i = tid; i < BM * 64; i += NT2) {
    int row = i >> 6, c0 = (i & 63) << 3;
    float sf[8], sr[8];
#pragma unroll
    for (int e = 0; e < 8; ++e) { sf[e] = p.bs0[c0 + e]; sr[e] = sf[e]; }
#pragma unroll
    for (int j = 0; j < 4; ++j) {
      int a = sIdx[row * 4 + j];
      short8 vf = *(const short8*)(p.p + ((size_t)a * 4 + j) * 512 + c0);
      short8 vr = *(const short8*)(p.p + ((size_t)a * 4 + (3 - j)) * 512 + c0);
#pragma unroll
      for (int e = 0; e < 8; ++e) { sf[e] += bf2f(vf[e]); sr[e] += bf2f(vr[e]); }
    }
    short8 of, orv;
#pragma unroll
    for (int e = 0; e < 8; ++e) { of[e] = f2bf(elu_f(sf[e])); orv[e] = f2bf(elu_f(sr[e])); }
    size_t off = (size_t)row * 1024 + ((c0 * 2) ^ ((row & 7) << 4));
    *(short8*)(sA + off) = of;
    *(short8*)(sB + off) = orv;
  }
  __syncthreads();

  layer_dual3<false>(sA, sB, p.W1, p.bs1, wv, lane);
  layer_dual3<false>(sA, sB, p.W2, p.bs2, wv, lane);
  layer_dual3<true >(sA, sB, p.W3, p.bs3, wv, lane);   // writes sym -> sA

  layer_single3(sA, p.Wt0, p.bt0, sA, sB, wv, lane);   // t0 = sym + elu(sym@Wt0)
  layer_single3(sB, p.Wt1, p.bt1, sB, sB, wv, lane);   // t1 = t0 + elu(t0@Wt1)
  layer_single3(sA, p.Wc0, p.bc0, sA, sA, wv, lane);   // c  = sym + elu(sym@Wc0)

  for (int idx = tid; idx < BM * 12; idx += NT2) {
    int row = idx / 12, jj = idx - row * 12;
    int j = (jj < 6) ? jj : jj - 6;
    const char* src = (jj < 6) ? sB : sA;
    const float* W = (jj < 6) ? p.Wt2 : p.Wc1;
    float acc = (jj < 6) ? p.bt2[j] : p.bc1[j];
    for (int c0 = 0; c0 < 512; c0 += 8) {
      short8 v = *(const short8*)(src + (size_t)row * 1024 + ((c0 * 2) ^ ((row & 7) << 4)));
#pragma unroll
      for (int e = 0; e < 8; ++e) acc += bf2f(v[e]) * W[(c0 + e) * 6 + j];
    }
    sSmall[row * 12 + jj] = acc;
  }
  __syncthreads();
  for (int idx = tid; idx < BM * 6; idx += NT2) {
    int row = idx / 6, j = idx - row * 6;
    int grow = r0 + row;
    if (grow < p.n_tors) {
      float score = sSmall[row * 12 + 6 + j];
      float coeff = sSmall[row * 12 + j];
      p.out[(size_t)grow * 6 + j] = score;
      p.out[(size_t)p.n_tors * 6 + (size_t)grow * 6 + j] =
          coeff * 0.001f * (1.0f / (1.0f + __expf(-score)));
    }
  }
}

// ================= LEGACY PATH (fallback if ws too small) =================

struct Params {
  const float* h;
  const int* idxs;
  const short *W0f, *W0r, *W1, *W2, *W3, *Wt0, *Wt1, *Wc0;
  const float *bs0, *bs1, *bs2, *bs3, *bt0, *bt1, *bt2, *bc0, *bc1;
  const float *Wt2, *Wc1;
  float* out;
  int n_tors;
};

__device__ __forceinline__ void layer_dual(char* hf, char* hr,
                                           const short* __restrict__ W,
                                           const float* __restrict__ bias,
                                           int wv, int lane) {
  f32x4 accf[4][4], accr[4][4];
  const f32x4 z = {0.f, 0.f, 0.f, 0.f};
#pragma unroll
  for (int rt = 0; rt < 4; ++rt)
#pragma unroll
    for (int cf = 0; cf < 4; ++cf) { accf[rt][cf] = z; accr[rt][cf] = z; }
  for (int kt = 0; kt < 16; ++kt) {
    short8 af[4], ar[4], b[4];
#pragma unroll
    for (int rt = 0; rt < 4; ++rt) {
      af[rt] = lds_afrag(hf, 1024, rt, kt, lane);
      ar[rt] = lds_afrag(hr, 1024, rt, kt, lane);
    }
#pragma unroll
    for (int cf = 0; cf < 4; ++cf) b[cf] = ldg_bfrag(W, 16, (wv << 2) + cf, kt, lane);
#pragma unroll
    for (int rt = 0; rt < 4; ++rt)
#pragma unroll
      for (int cf = 0; cf < 4; ++cf) {
        accf[rt][cf] = __builtin_amdgcn_mfma_f32_16x16x32_bf16(af[rt], b[cf], accf[rt][cf], 0, 0, 0);
        accr[rt][cf] = __builtin_amdgcn_mfma_f32_16x16x32_bf16(ar[rt], b[cf], accr[rt][cf], 0, 0, 0);
      }
  }
  float bcol[4];
#pragma unroll
  for (int cf = 0; cf < 4; ++cf) bcol[cf] = bias[(wv << 6) + (cf << 4) + (lane & 15)];
  __syncthreads();
#pragma unroll
  for (int rt = 0; rt < 4; ++rt)
#pragma unroll
    for (int cf = 0; cf < 4; ++cf) {
      int col = (wv << 6) + (cf << 4) + (lane & 15);
#pragma unroll
      for (int i = 0; i < 4; ++i) {
        int row = rt * 16 + ((lane >> 4) << 2) + i;
        size_t off = (size_t)row * 1024 + ((col * 2) ^ ((row & 7) << 4));
        short* pf = (short*)(hf + off);
        short* pr = (short*)(hr + off);
        *pf = f2bf(bf2f(*pf) + elu_f(accf[rt][cf][i] + bcol[cf]));
        *pr = f2bf(bf2f(*pr) + elu_f(accr[rt][cf][i] + bcol[cf]));
      }
    }
  __syncthreads();
}

__device__ __forceinline__ void layer_single(const char* in,
                                             const short* __restrict__ W,
                                             const float* __restrict__ bias,
                                             const char* res, char* out,
                                             int wv, int lane) {
  f32x4 acc[4][4];
  const f32x4 z = {0.f, 0.f, 0.f, 0.f};
#pragma unroll
  for (int rt = 0; rt < 4; ++rt)
#pragma unroll
    for (int cf = 0; cf < 4; ++cf) acc[rt][cf] = z;
  for (int kt = 0; kt < 16; ++kt) {
    short8 a[4], b[4];
#pragma unroll
    for (int rt = 0; rt < 4; ++rt) a[rt] = lds_afrag(in, 1024, rt, kt, lane);
#pragma unroll
    for (int cf = 0; cf < 4; ++cf) b[cf] = ldg_bfrag(W, 16, (wv << 2) + cf, kt, lane);
#pragma unroll
    for (int rt = 0; rt < 4; ++rt)
#pragma unroll
      for (int cf = 0; cf < 4; ++cf)
        acc[rt][cf] = __builtin_amdgcn_mfma_f32_16x16x32_bf16(a[rt], b[cf], acc[rt][cf], 0, 0, 0);
  }
  float bcol[4];
#pragma unroll
  for (int cf = 0; cf < 4; ++cf) bcol[cf] = bias[(wv << 6) + (cf << 4) + (lane & 15)];
  __syncthreads();
#pragma unroll
  for (int rt = 0; rt < 4; ++rt)
#pragma unroll
    for (int cf = 0; cf < 4; ++cf) {
      int col = (wv << 6) + (cf << 4) + (lane & 15);
#pragma unroll
      for (int i = 0; i < 4; ++i) {
        int row = rt * 16 + ((lane >> 4) << 2) + i;
        size_t off = (size_t)row * 1024 + ((col * 2) ^ ((row & 7) << 4));
        float v = elu_f(acc[rt][cf][i] + bcol[cf]) + bf2f(*(const short*)(res + off));
        *(short*)(out + off) = f2bf(v);
      }
    }
  __syncthreads();
}

__global__ __launch_bounds__(NTHREADS) void fused(Params p) {
  __shared__ char smem[BM * 2048];
  __shared__ float sSmall[BM * 12];
  char* sA = smem;
  char* sB = smem + BM * 1024;
  const int tid = threadIdx.x;
  const int lane = tid & 63;
  const int wv = tid >> 6;
  const int r0 = blockIdx.x * BM;

  for (int c = tid; c < BM * 128; c += NTHREADS) {
    int row = c >> 7;
    int col0 = (c & 127) << 3;
    int grow = r0 + row;
    short8 o;
    if (grow < p.n_tors) {
      int f = col0 >> 8;
      int cin = col0 & 255;
      int a = p.idxs[(size_t)grow * 4 + f];
      const float4* s4 = (const float4*)(p.h + (size_t)a * 256 + cin);
      float4 v0 = s4[0], v1 = s4[1];
      o[0] = f2bf(v0.x); o[1] = f2bf(v0.y); o[2] = f2bf(v0.z); o[3] = f2bf(v0.w);
      o[4] = f2bf(v1.x); o[5] = f2bf(v1.y); o[6] = f2bf(v1.z); o[7] = f2bf(v1.w);
    } else {
#pragma unroll
      for (int e = 0; e < 8; ++e) o[e] = 0;
    }
    *(short8*)(smem + (size_t)row * 2048 + ((col0 * 2) ^ ((row & 7) << 4))) = o;
  }
  __syncthreads();

  {
    f32x4 accf[4][4], accr[4][4];
    const f32x4 z = {0.f, 0.f, 0.f, 0.f};
#pragma unroll
    for (int rt = 0; rt < 4; ++rt)
#pragma unroll
      for (int cf = 0; cf < 4; ++cf) { accf[rt][cf] = z; accr[rt][cf] = z; }
    for (int kt = 0; kt < 32; ++kt) {
      short8 a[4], bfw[4], brw[4];
#pragma unroll
      for (int rt = 0; rt < 4; ++rt) a[rt] = lds_afrag(smem, 2048, rt, kt, lane);
#pragma unroll
      for (int cf = 0; cf < 4; ++cf) {
        bfw[cf] = ldg_bfrag(p.W0f, 32, (wv << 2) + cf, kt, lane);
        brw[cf] = ldg_bfrag(p.W0r, 32, (wv << 2) + cf, kt, lane);
      }
#pragma unroll
      for (int rt = 0; rt < 4; ++rt)
#pragma unroll
        for (int cf = 0; cf < 4; ++cf) {
          accf[rt][cf] = __builtin_amdgcn_mfma_f32_16x16x32_bf16(a[rt], bfw[cf], accf[rt][cf], 0, 0, 0);
          accr[rt][cf] = __builtin_amdgcn_mfma_f32_16x16x32_bf16(a[rt], brw[cf], accr[rt][cf], 0, 0, 0);
        }
    }
    float bcol[4];
#pragma unroll
    for (int cf = 0; cf < 4; ++cf) bcol[cf] = p.bs0[(wv << 6) + (cf << 4) + (lane & 15)];
    __syncthreads();
#pragma unroll
    for (int rt = 0; rt < 4; ++rt)
#pragma unroll
      for (int cf = 0; cf < 4; ++cf) {
        int col = (wv << 6) + (cf << 4) + (lane & 15);
#pragma unroll
        for (int i = 0; i < 4; ++i) {
          int row = rt * 16 + ((lane >> 4) << 2) + i;
          size_t off = (size_t)row * 1024 + ((col * 2) ^ ((row & 7) << 4));
          *(short*)(sA + off) = f2bf(elu_f(accf[rt][cf][i] + bcol[cf]));
          *(short*)(sB + off) = f2bf(elu_f(accr[rt][cf][i] + bcol[cf]));
        }
      }
    __syncthreads();
  }

  layer_dual(sA, sB, p.W1, p.bs1, wv, lane);
  layer_dual(sA, sB, p.W2, p.bs2, wv, lane);
  layer_dual(sA, sB, p.W3, p.bs3, wv, lane);

  for (int c = tid; c < BM * 64; c += NTHREADS) {
    int row = c >> 6;
    int col0 = (c & 63) << 3;
    size_t off = (size_t)row * 1024 + ((col0 * 2) ^ ((row & 7) << 4));
    short8 xa = *(short8*)(sA + off);
    short8 xb = *(short8*)(sB + off);
    short8 o;
#pragma unroll
    for (int e = 0; e < 8; ++e) o[e] = f2bf(bf2f(xa[e]) + bf2f(xb[e]));
    *(short8*)(sA + off) = o;
  }
  __syncthreads();

  layer_single(sA, p.Wt0, p.bt0, sA, sB, wv, lane);
  layer_single(sB, p.Wt1, p.bt1, sB, sB, wv, lane);
  layer_single(sA, p.Wc0, p.bc0, sA, sA, wv, lane);

  for (int idx = tid; idx < BM * 12; idx += NTHREADS) {
    int row = idx / 12, jj = idx - row * 12;
    int j = (jj < 6) ? jj : jj - 6;
    const char* src = (jj < 6) ? sB : sA;
    const float* W = (jj < 6) ? p.Wt2 : p.Wc1;
    float acc = (jj < 6) ? p.bt2[j] : p.bc1[j];
    for (int c0 = 0; c0 < 512; c0 += 8) {
      short8 v = *(const short8*)(src + (size_t)row * 1024 + ((c0 * 2) ^ ((row & 7) << 4)));
#pragma unroll
      for (int e = 0; e < 8; ++e) acc += bf2f(v[e]) * W[(c0 + e) * 6 + j];
    }
    sSmall[row * 12 + jj] = acc;
  }
  __syncthreads();
  for (int idx = tid; idx < BM * 6; idx += NTHREADS) {
    int row = idx / 6, j = idx - row * 6;
    int grow = r0 + row;
    if (grow < p.n_tors) {
      float score = sSmall[row * 12 + 6 + j];
      float coeff = sSmall[row * 12 + j];
      p.out[(size_t)grow * 6 + j] = score;
      p.out[(size_t)p.n_tors * 6 + (size_t)grow * 6 + j] =
          coeff * 0.001f * (1.0f / (1.0f + __expf(-score)));
    }
  }
}

// ================= LAUNCH =================

extern "C" void kernel_launch(void* const* d_in, const int* in_sizes, int n_in,
                              void* d_out, int out_size, void* d_ws, size_t ws_size,
                              hipStream_t stream) {
  const float* h   = (const float*)d_in[0];
  const int* idxs  = (const int*)d_in[1];
  const float* Ws0 = (const float*)d_in[2];
  const float* bs0 = (const float*)d_in[3];
  const float* Ws1 = (const float*)d_in[4];
  const float* bs1 = (const float*)d_in[5];
  const float* Ws2 = (const float*)d_in[6];
  const float* bs2 = (const float*)d_in[7];
  const float* Ws3 = (const float*)d_in[8];
  const float* bs3 = (const float*)d_in[9];
  const float* Wt0 = (const float*)d_in[10];
  const float* bt0 = (const float*)d_in[11];
  const float* Wt1 = (const float*)d_in[12];
  const float* bt1 = (const float*)d_in[13];
  const float* Wt2 = (const float*)d_in[14];
  const float* bt2 = (const float*)d_in[15];
  const float* Wc0 = (const float*)d_in[16];
  const float* bc0 = (const float*)d_in[17];
  const float* Wc1 = (const float*)d_in[18];
  const float* bc1 = (const float*)d_in[19];
  int n_tors = in_sizes[1] / 4;
  int n_atoms = in_sizes[0] / 256;

  auto pk = [&](const float* s, short* dmem, int K, int N, int rev) {
    int tiles = (N >> 4) * (K >> 5);
    pack_w<<<dim3((tiles + 3) / 4), dim3(256), 0, stream>>>(s, dmem, K, N, rev);
  };

  size_t pElems = (size_t)n_atoms * 4 * 512;
  size_t needNew = (pElems + 524288 + 6 * 262144) * sizeof(short);

  if (ws_size >= needNew) {
    short* ws = (short*)d_ws;
    short* pT  = ws;
    short* W0f = ws + pElems;
    short* W1  = W0f + 524288;
    short* W2  = W1 + 262144;
    short* W3  = W2 + 262144;
    short* Wt0c = W3 + 262144;
    short* Wt1c = Wt0c + 262144;
    short* Wc0c = Wt1c + 262144;

    pk(Ws0, W0f, 1024, 512, 0);
    pk(Ws1, W1, 512, 512, 0);
    pk(Ws2, W2, 512, 512, 0);
    pk(Ws3, W3, 512, 512, 0);
    pk(Wt0, Wt0c, 512, 512, 0);
    pk(Wt1, Wt1c, 512, 512, 0);
    pk(Wc0, Wc0c, 512, 512, 0);

    atom_pre<<<dim3((n_atoms + BM - 1) / BM), dim3(NTHREADS), 0, stream>>>(h, W0f, pT, n_atoms);

    P2 p;
    p.idxs = idxs; p.p = pT;
    p.W1 = W1; p.W2 = W2; p.W3 = W3;
    p.Wt0 = Wt0c; p.Wt1 = Wt1c; p.Wc0 = Wc0c;
    p.bs0 = bs0; p.bs1 = bs1; p.bs2 = bs2; p.bs3 = bs3;
    p.bt0 = bt0; p.bt1 = bt1; p.bt2 = bt2; p.bc0 = bc0; p.bc1 = bc1;
    p.Wt2 = Wt2; p.Wc1 = Wc1;
    p.out = (float*)d_out; p.n_tors = n_tors;

    fused2<<<dim3((n_tors + BM - 1) / BM), dim3(NT2), 0, stream>>>(p);
  } else {
    short* ws = (short*)d_ws;
    short* W0f = ws;
    short* W0r = ws + 524288;
    short* W1  = ws + 1048576;
    short* W2  = W1 + 262144;
    short* W3  = W2 + 262144;
    short* Wt0c = W3 + 262144;
    short* Wt1c = Wt0c + 262144;
    short* Wc0c = Wt1c + 262144;

    pk(Ws0, W0f, 1024, 512, 0);
    pk(Ws0, W0r, 1024, 512, 1);
    pk(Ws1, W1, 512, 512, 0);
    pk(Ws2, W2, 512, 512, 0);
    pk(Ws3, W3, 512, 512, 0);
    pk(Wt0, Wt0c, 512, 512, 0);
    pk(Wt1, Wt1c, 512, 512, 0);
    pk(Wc0, Wc0c, 512, 512, 0);

    Params p;
    p.h = h; p.idxs = idxs;
    p.W0f = W0f; p.W0r = W0r; p.W1 = W1; p.W2 = W2; p.W3 = W3;
    p.Wt0 = Wt0c; p.Wt1 = Wt1c; p.Wc0 = Wc0c;
    p.bs0 = bs0; p.bs1 = bs1; p.bs2 = bs2; p.bs3 = bs3;
    p.bt0 = bt0; p.bt1 = bt1; p.bt2 = bt2; p.bc0 = bc0; p.bc1 = bc1;
    p.Wt2 = Wt2; p.Wc1 = Wc1;
    p.out = (float*)d_out; p.n_tors = n_tors;

    fused<<<dim3((n_tors + BM - 1) / BM), dim3(NTHREADS), 0, stream>>>(p);
  }
}